// Round 5
// baseline (332.078 us; speedup 1.0000x reference)
//
#include <hip/hip_runtime.h>
#include <math.h>

// ---------------------------------------------------------------------------
// Round 16 — K1 epilogue coalescing + XCD-aware attn swizzle.
//   K0 (prep): X, Wqkv, Wout -> bf16 once; RoPE cos/sin tables (2048x32 f32).
//   K1: qkv GEMM (+table RoPE). Epilogue now stages each wave's 64x64 output
//       tile in wave-private LDS (padded strides), then writes fully
//       coalesced: Q/K as 4KB contiguous runs (was 64x 2B scalar stores),
//       V^T as 64B line-aligned d-row chunks (was 16x scattered 8B, 8x amp).
//   K2: causal flash attention; 1-D grid with XCD swizzle so all 16 blocks
//       of one (b,h) head land on the same XCD -> K/V L2-resident (T1).
//   K3: out = att @ Woutb^T -> d_out FP32
// ---------------------------------------------------------------------------

typedef __attribute__((ext_vector_type(8))) __bf16 bf16x8;
typedef __attribute__((ext_vector_type(8))) short  short8;
typedef __attribute__((ext_vector_type(4))) short  s16x4;
typedef __attribute__((ext_vector_type(4))) float  f32x4;

#define MFMA16(a, b, c) __builtin_amdgcn_mfma_f32_16x16x32_bf16((a), (b), (c), 0, 0, 0)

static constexpr int    BATCH = 4;
static constexpr int    SEQ   = 2048;
static constexpr int    DIM   = 1024;
static constexpr int    NH    = 16;
static constexpr int    HD    = 64;
static constexpr size_t BHSD  = (size_t)BATCH * NH * SEQ * HD;  // 8388608
static constexpr float  NEGINF = -1e9f;
static constexpr int    PS_LD  = 72;   // padded k-stride for Ps (16B-aligned reads)
static constexpr int    EP_W   = 2560; // per-wave epilogue LDS slice (shorts)

__device__ __forceinline__ short f2bf(float f) {
    union { float f; unsigned u; } v; v.f = f;
    unsigned r = v.u + 0x7fffu + ((v.u >> 16) & 1u);  // RNE
    return (short)(r >> 16);
}

__device__ __forceinline__ short8 cvt8(const f32x4 lo, const f32x4 hi) {
    short8 r;
    r[0] = f2bf(lo[0]); r[1] = f2bf(lo[1]); r[2] = f2bf(lo[2]); r[3] = f2bf(lo[3]);
    r[4] = f2bf(hi[0]); r[5] = f2bf(hi[1]); r[6] = f2bf(hi[2]); r[7] = f2bf(hi[3]);
    return r;
}

template <bool F32>
__device__ __forceinline__ short8 ld8(const void* p, size_t row, int K, int k) {
    if constexpr (F32) {
        const float* f = (const float*)p;
        f32x4 lo = *(const f32x4*)&f[row * (size_t)K + k];
        f32x4 hi = *(const f32x4*)&f[row * (size_t)K + k + 4];
        return cvt8(lo, hi);
    } else {
        const short* s = (const short*)p;
        return *(const short8*)&s[row * (size_t)K + k];
    }
}

// async HBM->LDS, 16 B per lane. LDS dest = wave-uniform base + lane*16.
__device__ __forceinline__ void gload16(const void* g, void* lds) {
    __builtin_amdgcn_global_load_lds(
        (const __attribute__((address_space(1))) void*)g,
        (__attribute__((address_space(3))) void*)lds, 16, 0, 0);
}

// ---------------------------------------------------------------------------
// K0: one-shot bf16 conversion of X/Wqkv/Wout + RoPE trig tables.
// ---------------------------------------------------------------------------
__global__ __launch_bounds__(256) void prep_kernel(
    const float* __restrict__ X, const float* __restrict__ Wq,
    const float* __restrict__ Wo, short* __restrict__ Xb,
    short* __restrict__ Wqb, short* __restrict__ Wob,
    float* __restrict__ cosT, float* __restrict__ sinT) {
    const int stride = gridDim.x * blockDim.x;
    for (int idx = blockIdx.x * blockDim.x + threadIdx.x; idx < 3211264; idx += stride) {
        if (idx < 3145728) {
            const float* src; short* dst; int off;
            if (idx < 2097152)      { src = X;  dst = Xb;  off = idx; }
            else if (idx < 2883584) { src = Wq; dst = Wqb; off = idx - 2097152; }
            else                    { src = Wo; dst = Wob; off = idx - 2883584; }
            f32x4 v = *(const f32x4*)&src[(size_t)off * 4];
            s16x4 r;
            r[0] = f2bf(v[0]); r[1] = f2bf(v[1]); r[2] = f2bf(v[2]); r[3] = f2bf(v[3]);
            *(s16x4*)&dst[(size_t)off * 4] = r;
        } else {
            int r = idx - 3145728;              // 0..65535
            int s = r >> 5, d = r & 31;
            float ang = (float)s * __expf(-0.28782313662425574f * (float)d);
            float sn, cs;
            sincosf(ang, &sn, &cs);
            cosT[r] = cs; sinT[r] = sn;
        }
    }
}

// ---------------------------------------------------------------------------
// GEMM core (fallback, reg-staged): C(128x128) += A(128xK) * B(128xK)^T.
// ---------------------------------------------------------------------------
template <bool AF32, bool BF32>
__device__ __forceinline__ void gemm128_core(
    const void* __restrict__ A, const void* __restrict__ B, int K,
    short* As, short* Bs, int bm, int bn, f32x4 acc[4][4]) {
    const int tid  = threadIdx.x;
    const int lane = tid & 63;
    const int wave = tid >> 6;
    const int quad = lane >> 4;
    const int col  = lane & 15;
    const int wm   = (wave & 1) * 64;
    const int wn   = (wave >> 1) * 64;

    const int r0 = tid >> 2;
    const int r1 = (tid + 256) >> 2;
    const int ko = (tid & 3) * 8;

#pragma unroll
    for (int i = 0; i < 4; ++i)
#pragma unroll
        for (int j = 0; j < 4; ++j) acc[i][j] = f32x4{0.f, 0.f, 0.f, 0.f};

#pragma unroll 1
    for (int k0 = 0; k0 < K; k0 += 32) {
        short8 a0 = ld8<AF32>(A, (size_t)(bm + r0), K, k0 + ko);
        short8 a1 = ld8<AF32>(A, (size_t)(bm + r1), K, k0 + ko);
        short8 b0 = ld8<BF32>(B, (size_t)(bn + r0), K, k0 + ko);
        short8 b1 = ld8<BF32>(B, (size_t)(bn + r1), K, k0 + ko);
        __syncthreads();
        *(short8*)&As[tid * 8]         = a0;
        *(short8*)&As[(tid + 256) * 8] = a1;
        *(short8*)&Bs[tid * 8]         = b0;
        *(short8*)&Bs[(tid + 256) * 8] = b1;
        __syncthreads();

        bf16x8 af[4], bfr[4];
#pragma unroll
        for (int i = 0; i < 4; ++i)
            af[i] = *(const bf16x8*)&As[(wm + i * 16 + col) * 32 + quad * 8];
#pragma unroll
        for (int j = 0; j < 4; ++j)
            bfr[j] = *(const bf16x8*)&Bs[(wn + j * 16 + col) * 32 + quad * 8];
#pragma unroll
        for (int i = 0; i < 4; ++i)
#pragma unroll
            for (int j = 0; j < 4; ++j)
                acc[i][j] = MFMA16(af[i], bfr[j], acc[i][j]);
    }
}

// ---------------------------------------------------------------------------
// GEMM core (bf16, global_load_lds staging — m97 structure).
// ---------------------------------------------------------------------------
__device__ __forceinline__ void gemm128_lds(
    const short* __restrict__ A, const short* __restrict__ B, int K,
    short* As, short* Bs, int bm, int bn, f32x4 acc[4][4]) {
    const int tid  = threadIdx.x;
    const int lane = tid & 63;
    const int wave = tid >> 6;
    const int quad = lane >> 4;
    const int col  = lane & 15;
    const int wm   = (wave & 1) * 64;
    const int wn   = (wave >> 1) * 64;

    const int r0 = tid >> 2;            // 0..63
    const int r1 = r0 + 64;             // 64..127
    const int ko = (tid & 3) * 8;

    const short* A0 = &A[(size_t)(bm + r0) * K + ko];
    const short* A1 = &A[(size_t)(bm + r1) * K + ko];
    const short* B0 = &B[(size_t)(bn + r0) * K + ko];
    const short* B1 = &B[(size_t)(bn + r1) * K + ko];

    short* As0 = &As[wave * 512];          // wave base, first half
    short* As1 = &As[2048 + wave * 512];   // second half (+4096 B)
    short* Bs0 = &Bs[wave * 512];
    short* Bs1 = &Bs[2048 + wave * 512];

#pragma unroll
    for (int i = 0; i < 4; ++i)
#pragma unroll
        for (int j = 0; j < 4; ++j) acc[i][j] = f32x4{0.f, 0.f, 0.f, 0.f};

#pragma unroll 1
    for (int k0 = 0; k0 < K; k0 += 32) {
        __syncthreads();                   // prev step's LDS reads done
        gload16(A0 + k0, As0);
        gload16(A1 + k0, As1);
        gload16(B0 + k0, Bs0);
        gload16(B1 + k0, Bs1);
        __syncthreads();                   // vmcnt drained -> tile staged

        bf16x8 af[4], bfr[4];
#pragma unroll
        for (int i = 0; i < 4; ++i)
            af[i] = *(const bf16x8*)&As[(wm + i * 16 + col) * 32 + quad * 8];
#pragma unroll
        for (int j = 0; j < 4; ++j)
            bfr[j] = *(const bf16x8*)&Bs[(wn + j * 16 + col) * 32 + quad * 8];
#pragma unroll
        for (int i = 0; i < 4; ++i)
#pragma unroll
            for (int j = 0; j < 4; ++j)
                acc[i][j] = MFMA16(af[i], bfr[j], acc[i][j]);
    }
}

// ---------------------------------------------------------------------------
// K1: QKV GEMM + RoPE. grid=(24, 64). Q,K row-major [B,H,S,D]; V transposed
// [B,H,D,S]. Epilogue: wave-private LDS staging -> coalesced stores.
// Per wave the C-tile is 64 rows (s) x 64 cols (the head's full d-range), so
// Q/K output is a CONTIGUOUS 8KB region; VT output is 64 d-rows of 64B.
// Staged in 2 halves of 32 rows (Ep slice = 5KB/wave). No barriers needed:
// each wave reads only what it wrote (per-wave LDS pipe is in-order).
// ---------------------------------------------------------------------------
template <bool PRE>
__global__ __launch_bounds__(256, 2) void qkv_rope_kernel(
    const void* __restrict__ X, const void* __restrict__ W,
    const float* __restrict__ cosT, const float* __restrict__ sinT,
    short* __restrict__ Qo, short* __restrict__ Ko, short* __restrict__ VT) {
    __shared__ __align__(16) short As[128 * 32];
    __shared__ __align__(16) short Bs[128 * 32];
    __shared__ __align__(16) short Ep[4 * EP_W];
    const int bm = blockIdx.y * 128, bn = blockIdx.x * 128;
    const int lane = threadIdx.x & 63, wave = threadIdx.x >> 6;
    const int quad = lane >> 4, col = lane & 15;
    const int wm = (wave & 1) * 64, wn = (wave >> 1) * 64;

    f32x4 acc[4][4];
    if constexpr (PRE)
        gemm128_lds((const short*)X, (const short*)W, 1024, As, Bs, bm, bn, acc);
    else
        gemm128_core<true, true>(X, W, 1024, As, Bs, bm, bn, acc);

    const int n0    = bn + wn;       // 64-aligned -> which/h wave-uniform
    const int which = n0 >> 10;      // 0=q 1=k 2=v
    const int h     = (n0 >> 6) & 15;
    short* Lw = &Ep[wave * EP_W];

    if (which == 2) {
        // V^T: stage transposed [d][s_local] (stride 40, 16B-aligned rows),
        // then each lane writes one 64B line-aligned d-row chunk.
#pragma unroll
        for (int ih = 0; ih < 2; ++ih) {
            const int m0 = bm + wm + ih * 32;
            const int b0 = m0 >> 11, s0 = m0 & 2047;
#pragma unroll
            for (int ii = 0; ii < 2; ++ii) {
                const int i  = ih * 2 + ii;
                const int sl = ii * 16 + quad * 4;
#pragma unroll
                for (int j = 0; j < 4; ++j) {
                    s16x4 pk;
                    pk[0] = f2bf(acc[i][j][0]); pk[1] = f2bf(acc[i][j][1]);
                    pk[2] = f2bf(acc[i][j][2]); pk[3] = f2bf(acc[i][j][3]);
                    *(s16x4*)&Lw[(j * 16 + col) * 40 + sl] = pk;
                }
            }
            const size_t rowb = (size_t)(b0 * NH + h) * HD;
            short* dv = &VT[(rowb + lane) * (size_t)SEQ + s0];
#pragma unroll
            for (int k = 0; k < 4; ++k)
                *(short8*)&dv[k * 8] = *(const short8*)&Lw[lane * 40 + k * 8];
        }
    } else {
        short* dst = which ? Ko : Qo;
#pragma unroll
        for (int ih = 0; ih < 2; ++ih) {
            const int m0 = bm + wm + ih * 32;
            const int b0 = m0 >> 11, s0 = m0 & 2047;
#pragma unroll
            for (int ii = 0; ii < 2; ++ii) {
                const int i = ih * 2 + ii;
#pragma unroll
                for (int reg = 0; reg < 4; ++reg) {
                    const int r = ii * 16 + quad * 4 + reg;
                    const int s = s0 + r;
#pragma unroll
                    for (int j = 0; j < 2; ++j) {
                        const int d1 = j * 16 + col;                 // 0..31
                        float sn, cs;
                        if constexpr (PRE) {
                            cs = cosT[(s << 5) + d1];
                            sn = sinT[(s << 5) + d1];
                        } else {
                            float inv = __expf(-0.28782313662425574f * (float)d1);
                            sincosf((float)s * inv, &sn, &cs);
                        }
                        float x1 = acc[i][j][reg];
                        float x2 = acc[i][j + 2][reg];
                        Lw[r * 72 + d1]      = f2bf(x1 * cs - x2 * sn);
                        Lw[r * 72 + d1 + 32] = f2bf(x1 * sn + x2 * cs);
                    }
                }
            }
            // readback: lane -> (row, half-row); 4KB contiguous global run
            const int rr = lane >> 1, c0 = (lane & 1) * 32;
            short* dq = dst + ((size_t)(b0 * NH + h) * SEQ + s0) * HD + rr * HD + c0;
#pragma unroll
            for (int k = 0; k < 4; ++k)
                *(short8*)&dq[k * 8] = *(const short8*)&Lw[rr * 72 + c0 + k * 8];
        }
    }
}

// ---------------------------------------------------------------------------
// K2: causal flash attention. grid=(1024): 1-D with XCD swizzle — all 16
// blocks of one (b,h) head land on the same XCD (8 heads per XCD) so K/V
// stay L2-resident (T1; bijective since 1024 = 8*128). Block handles
// q-tiles {bx, 31-bx} -> exactly 33 t-iterations (balanced). Kt/Vt
// XOR-swizzled (conflicts 2.7e7 -> 1.1e6). Diag-only masking.
// ---------------------------------------------------------------------------
__global__ __launch_bounds__(256, 2) void attn_kernel(
    const short* __restrict__ Q, const short* __restrict__ K,
    const short* __restrict__ VT, short* __restrict__ att) {
    const int id = (int)blockIdx.x;
    const int sw = (id & 7) * 128 + (id >> 3);     // XCD-contiguous remap
    const int bx = sw & 15;
    const int h  = (sw >> 4) & 15;
    const int b  = sw >> 8;
    const int tid = threadIdx.x, wave = tid >> 6, lane = tid & 63;
    const int quad = lane >> 4, col = lane & 15;
    const size_t hoff = (size_t)(b * NH + h) * SEQ * HD;
    const short* Qp  = Q + hoff;
    const short* Kp  = K + hoff;
    const short* VTp = VT + hoff;   // [HD][SEQ]

    __shared__ __align__(16) short Kt[64 * 64];        // [t][d], swizzled
    __shared__ __align__(16) short Vt[64 * 64];        // [d][t], swizzled
    __shared__ __align__(16) short Ps[4 * 16 * PS_LD]; // per-wave P [m][k], padded

    const int r0 = tid >> 3;            // 0..31
    const int r1 = r0 + 32;             // 32..63  (r1&7 == r0&7)
    const int c8 = (tid & 7) * 8;
    const int cs = c8 ^ ((r0 & 7) << 3);            // swizzled store column
    const int swc = (col & 7) << 3;
    const int cA  = (quad * 8) ^ swc;               // first half of row
    const int cB  = (32 + quad * 8) ^ swc;          // second half of row
    short* Pw = &Ps[wave * 16 * PS_LD];

#pragma unroll 1
    for (int pass = 0; pass < 2; ++pass) {
        const int qt = pass ? 31 - bx : bx;
        const int q0 = qt * 64 + wave * 16;

        bf16x8 aq0 = *(const bf16x8*)&Qp[(q0 + col) * HD + quad * 8];
        bf16x8 aq1 = *(const bf16x8*)&Qp[(q0 + col) * HD + 32 + quad * 8];

        float m_i[4], l_i[4];
        f32x4 o[4];
#pragma unroll
        for (int r = 0; r < 4; ++r) { m_i[r] = NEGINF; l_i[r] = 0.f; o[r] = f32x4{0.f, 0.f, 0.f, 0.f}; }

        // prefetch tile 0
        short8 ka = *(const short8*)&Kp[r0 * HD + c8];
        short8 kb = *(const short8*)&Kp[r1 * HD + c8];
        short8 va = *(const short8*)&VTp[(size_t)r0 * SEQ + c8];
        short8 vb = *(const short8*)&VTp[(size_t)r1 * SEQ + c8];

#pragma unroll 1
        for (int t = 0; t <= qt; ++t) {
            const int kt = t * 64;
            __syncthreads();                       // prev iter's LDS reads done
            *(short8*)&Kt[r0 * 64 + cs] = ka;
            *(short8*)&Kt[r1 * 64 + cs] = kb;
            *(short8*)&Vt[r0 * 64 + cs] = va;
            *(short8*)&Vt[r1 * 64 + cs] = vb;
            __syncthreads();                       // tile staged

            if (t < qt) {                          // prefetch next tile
                const int kn = kt + 64;
                ka = *(const short8*)&Kp[(kn + r0) * HD + c8];
                kb = *(const short8*)&Kp[(kn + r1) * HD + c8];
                va = *(const short8*)&VTp[(size_t)r0 * SEQ + kn + c8];
                vb = *(const short8*)&VTp[(size_t)r1 * SEQ + kn + c8];
            }

            // S = Q K^T / 8; mask only needed on the diagonal tile
            float p[4][4];  // [jn][reg]
#pragma unroll
            for (int jn = 0; jn < 4; ++jn) {
                f32x4  s  = f32x4{0.f, 0.f, 0.f, 0.f};
                bf16x8 b0 = *(const bf16x8*)&Kt[(jn * 16 + col) * 64 + cA];
                bf16x8 b1 = *(const bf16x8*)&Kt[(jn * 16 + col) * 64 + cB];
                s = MFMA16(aq0, b0, s);
                s = MFMA16(aq1, b1, s);
                if (t == qt) {                     // wave-uniform branch
#pragma unroll
                    for (int reg = 0; reg < 4; ++reg) {
                        int qr = wave * 16 + quad * 4 + reg;   // local row
                        int kc = jn * 16 + col;                // local col
                        p[jn][reg] = (kc <= qr) ? s[reg] * 0.125f : NEGINF;
                    }
                } else {
#pragma unroll
                    for (int reg = 0; reg < 4; ++reg) p[jn][reg] = s[reg] * 0.125f;
                }
            }

            // online softmax (row stats across the 16 lanes of the quad group)
            float alpha[4];
#pragma unroll
            for (int reg = 0; reg < 4; ++reg) {
                float mx = fmaxf(fmaxf(p[0][reg], p[1][reg]), fmaxf(p[2][reg], p[3][reg]));
#pragma unroll
                for (int off = 8; off >= 1; off >>= 1) mx = fmaxf(mx, __shfl_xor(mx, off, 64));
                float mn   = fmaxf(m_i[reg], mx);
                alpha[reg] = __expf(m_i[reg] - mn);
                float rs = 0.f;
#pragma unroll
                for (int jn = 0; jn < 4; ++jn) { p[jn][reg] = __expf(p[jn][reg] - mn); rs += p[jn][reg]; }
#pragma unroll
                for (int off = 8; off >= 1; off >>= 1) rs += __shfl_xor(rs, off, 64);
                l_i[reg] = l_i[reg] * alpha[reg] + rs;
                m_i[reg] = mn;
            }
#pragma unroll
            for (int jd = 0; jd < 4; ++jd)
#pragma unroll
                for (int reg = 0; reg < 4; ++reg) o[jd][reg] *= alpha[reg];

            // P: C-layout -> wave-private LDS [m][k] (padded stride; no barrier)
#pragma unroll
            for (int jn = 0; jn < 4; ++jn)
#pragma unroll
                for (int reg = 0; reg < 4; ++reg)
                    Pw[(quad * 4 + reg) * PS_LD + jn * 16 + col] = f2bf(p[jn][reg]);

            // O += P V
            bf16x8 ap0 = *(const bf16x8*)&Pw[col * PS_LD + quad * 8];
            bf16x8 ap1 = *(const bf16x8*)&Pw[col * PS_LD + 32 + quad * 8];
#pragma unroll
            for (int jd = 0; jd < 4; ++jd) {
                bf16x8 bv0 = *(const bf16x8*)&Vt[(jd * 16 + col) * 64 + cA];
                bf16x8 bv1 = *(const bf16x8*)&Vt[(jd * 16 + col) * 64 + cB];
                o[jd] = MFMA16(ap0, bv0, o[jd]);
                o[jd] = MFMA16(ap1, bv1, o[jd]);
            }
        }

        // epilogue: att[b, s, h*64 + d] bf16
#pragma unroll
        for (int jd = 0; jd < 4; ++jd)
#pragma unroll
            for (int reg = 0; reg < 4; ++reg) {
                int s = q0 + quad * 4 + reg;
                att[((size_t)(b * SEQ + s)) * DIM + h * HD + jd * 16 + col] =
                    f2bf(o[jd][reg] / l_i[reg]);
            }
    }
}

// ---------------------------------------------------------------------------
// K3: out = att @ Wout^T, FP32 output. grid=(8, 64). PRE: bf16 Wout + gload.
// ---------------------------------------------------------------------------
template <bool PRE>
__global__ __launch_bounds__(256, 2) void out_gemm_kernel(
    const short* __restrict__ A, const void* __restrict__ W,
    float* __restrict__ out) {
    __shared__ __align__(16) short As[128 * 32];
    __shared__ __align__(16) short Bs[128 * 32];
    const int bm = blockIdx.y * 128, bn = blockIdx.x * 128;
    const int lane = threadIdx.x & 63, wave = threadIdx.x >> 6;
    const int quad = lane >> 4, col = lane & 15;
    const int wm = (wave & 1) * 64, wn = (wave >> 1) * 64;

    f32x4 acc[4][4];
    if constexpr (PRE)
        gemm128_lds(A, (const short*)W, 1024, As, Bs, bm, bn, acc);
    else
        gemm128_core<false, true>(A, W, 1024, As, Bs, bm, bn, acc);

#pragma unroll
    for (int i = 0; i < 4; ++i)
#pragma unroll
        for (int reg = 0; reg < 4; ++reg) {
            int    m    = bm + wm + i * 16 + quad * 4 + reg;
            size_t base = (size_t)m * DIM + bn + wn;
#pragma unroll
            for (int j = 0; j < 4; ++j)
                out[base + j * 16 + col] = acc[i][j][reg];   // FP32 store
        }
}

// ---------------------------------------------------------------------------
extern "C" void kernel_launch(void* const* d_in, const int* in_sizes, int n_in,
                              void* d_out, int out_size, void* d_ws, size_t ws_size,
                              hipStream_t stream) {
    // Pointer assignment by unique element counts:
    //   x=8388608, mask=4194304 (tril, unused), Wqkv=3145728, Wout=1048576
    const float* x    = nullptr;
    const float* Wqkv = nullptr;
    const float* Wout = nullptr;
    for (int i = 0; i < n_in; ++i) {
        switch (in_sizes[i]) {
            case 8388608: x    = (const float*)d_in[i]; break;
            case 3145728: Wqkv = (const float*)d_in[i]; break;
            case 1048576: Wout = (const float*)d_in[i]; break;
            default: break;
        }
    }
    if (!x || !Wqkv || !Wout) return;

    short* Q  = (short*)d_ws;           // 16 MiB
    short* K  = Q + BHSD;               // 16 MiB
    short* VT = K + BHSD;               // 16 MiB (V transposed [B,H,D,S])
    float* out = (float*)d_out;

    const size_t need_pre = (size_t)4 * BHSD * sizeof(short)   // Q,K,VT,att
                          + BHSD * sizeof(short)               // Xb
                          + (size_t)3145728 * sizeof(short)    // Wqkvb
                          + (size_t)1048576 * sizeof(short)    // Woutb
                          + (size_t)2 * 65536 * sizeof(float); // tables

    if (ws_size >= need_pre) {
        short* att  = VT + BHSD;
        short* Xb   = att + BHSD;
        short* Wqb  = Xb + BHSD;
        short* Wob  = Wqb + 3145728;
        float* cosT = (float*)(Wob + 1048576);
        float* sinT = cosT + 65536;

        prep_kernel<<<dim3(2048), 256, 0, stream>>>(x, Wqkv, Wout, Xb, Wqb, Wob, cosT, sinT);
        qkv_rope_kernel<true><<<dim3(24, 64), 256, 0, stream>>>(Xb, Wqb, cosT, sinT, Q, K, VT);
        attn_kernel<<<dim3(1024), 256, 0, stream>>>(Q, K, VT, att);
        out_gemm_kernel<true><<<dim3(8, 64), 256, 0, stream>>>(att, Wob, out);
    } else {
        // Fallback: fp32 staging + inline RoPE.
        qkv_rope_kernel<false><<<dim3(24, 64), 256, 0, stream>>>(
            x, Wqkv, nullptr, nullptr, Q, K, VT);

        const bool direct = ws_size >= (size_t)4 * BHSD * sizeof(short);
        short* att_dst = direct ? (VT + BHSD) : (short*)d_out;
        attn_kernel<<<dim3(1024), 256, 0, stream>>>(Q, K, VT, att_dst);

        short* att = att_dst;
        if (!direct) {
            att = (short*)d_ws;         // reuse Q region after K2
            hipMemcpyAsync(att, att_dst, BHSD * sizeof(short), hipMemcpyDeviceToDevice, stream);
        }
        out_gemm_kernel<false><<<dim3(8, 64), 256, 0, stream>>>(att, Wout, out);
    }
}

// Round 6
// 297.197 us; speedup vs baseline: 1.1174x; 1.1174x over previous
//
#include <hip/hip_runtime.h>
#include <math.h>

// ---------------------------------------------------------------------------
// Round 17 — revert round-16 experiments (XCD swizzle hurt: L2 locality
// confirmed by FETCH 252->24.6 MB but attn is latency-bound, not fetch-bound;
// epilogue LDS staging neutral). Add m214-proven softmax thinning:
//   - T13 defer-max THR=8: skip max-reduce/alpha/rescale when no lane's
//     tile-max exceeds m_i+8 (common path for gaussian scores).
//   - per-lane partial l_i, reduced once in the epilogue (alpha is
//     row-uniform so partials scale correctly).
//   K0 (prep): X, Wqkv, Wout -> bf16; RoPE cos/sin tables.
//   K1: qkv GEMM (+table RoPE), gload_lds staging, direct stores (round-4).
//   K2: flash attention, paired q-tiles {bx,31-bx}, XOR-swizzled Kt/Vt.
//   K3: out = att @ Woutb^T -> FP32.
// ---------------------------------------------------------------------------

typedef __attribute__((ext_vector_type(8))) __bf16 bf16x8;
typedef __attribute__((ext_vector_type(8))) short  short8;
typedef __attribute__((ext_vector_type(4))) short  s16x4;
typedef __attribute__((ext_vector_type(4))) float  f32x4;

#define MFMA16(a, b, c) __builtin_amdgcn_mfma_f32_16x16x32_bf16((a), (b), (c), 0, 0, 0)

static constexpr int    BATCH = 4;
static constexpr int    SEQ   = 2048;
static constexpr int    DIM   = 1024;
static constexpr int    NH    = 16;
static constexpr int    HD    = 64;
static constexpr size_t BHSD  = (size_t)BATCH * NH * SEQ * HD;  // 8388608
static constexpr float  NEGINF = -1e9f;
static constexpr int    PS_LD  = 72;   // padded k-stride for Ps (16B-aligned reads)

__device__ __forceinline__ short f2bf(float f) {
    union { float f; unsigned u; } v; v.f = f;
    unsigned r = v.u + 0x7fffu + ((v.u >> 16) & 1u);  // RNE
    return (short)(r >> 16);
}

__device__ __forceinline__ short8 cvt8(const f32x4 lo, const f32x4 hi) {
    short8 r;
    r[0] = f2bf(lo[0]); r[1] = f2bf(lo[1]); r[2] = f2bf(lo[2]); r[3] = f2bf(lo[3]);
    r[4] = f2bf(hi[0]); r[5] = f2bf(hi[1]); r[6] = f2bf(hi[2]); r[7] = f2bf(hi[3]);
    return r;
}

template <bool F32>
__device__ __forceinline__ short8 ld8(const void* p, size_t row, int K, int k) {
    if constexpr (F32) {
        const float* f = (const float*)p;
        f32x4 lo = *(const f32x4*)&f[row * (size_t)K + k];
        f32x4 hi = *(const f32x4*)&f[row * (size_t)K + k + 4];
        return cvt8(lo, hi);
    } else {
        const short* s = (const short*)p;
        return *(const short8*)&s[row * (size_t)K + k];
    }
}

// async HBM->LDS, 16 B per lane. LDS dest = wave-uniform base + lane*16.
__device__ __forceinline__ void gload16(const void* g, void* lds) {
    __builtin_amdgcn_global_load_lds(
        (const __attribute__((address_space(1))) void*)g,
        (__attribute__((address_space(3))) void*)lds, 16, 0, 0);
}

// ---------------------------------------------------------------------------
// K0: one-shot bf16 conversion of X/Wqkv/Wout + RoPE trig tables.
// ---------------------------------------------------------------------------
__global__ __launch_bounds__(256) void prep_kernel(
    const float* __restrict__ X, const float* __restrict__ Wq,
    const float* __restrict__ Wo, short* __restrict__ Xb,
    short* __restrict__ Wqb, short* __restrict__ Wob,
    float* __restrict__ cosT, float* __restrict__ sinT) {
    const int stride = gridDim.x * blockDim.x;
    for (int idx = blockIdx.x * blockDim.x + threadIdx.x; idx < 3211264; idx += stride) {
        if (idx < 3145728) {
            const float* src; short* dst; int off;
            if (idx < 2097152)      { src = X;  dst = Xb;  off = idx; }
            else if (idx < 2883584) { src = Wq; dst = Wqb; off = idx - 2097152; }
            else                    { src = Wo; dst = Wob; off = idx - 2883584; }
            f32x4 v = *(const f32x4*)&src[(size_t)off * 4];
            s16x4 r;
            r[0] = f2bf(v[0]); r[1] = f2bf(v[1]); r[2] = f2bf(v[2]); r[3] = f2bf(v[3]);
            *(s16x4*)&dst[(size_t)off * 4] = r;
        } else {
            int r = idx - 3145728;              // 0..65535
            int s = r >> 5, d = r & 31;
            float ang = (float)s * __expf(-0.28782313662425574f * (float)d);
            float sn, cs;
            sincosf(ang, &sn, &cs);
            cosT[r] = cs; sinT[r] = sn;
        }
    }
}

// ---------------------------------------------------------------------------
// GEMM core (fallback, reg-staged): C(128x128) += A(128xK) * B(128xK)^T.
// ---------------------------------------------------------------------------
template <bool AF32, bool BF32>
__device__ __forceinline__ void gemm128_core(
    const void* __restrict__ A, const void* __restrict__ B, int K,
    short* As, short* Bs, int bm, int bn, f32x4 acc[4][4]) {
    const int tid  = threadIdx.x;
    const int lane = tid & 63;
    const int wave = tid >> 6;
    const int quad = lane >> 4;
    const int col  = lane & 15;
    const int wm   = (wave & 1) * 64;
    const int wn   = (wave >> 1) * 64;

    const int r0 = tid >> 2;
    const int r1 = (tid + 256) >> 2;
    const int ko = (tid & 3) * 8;

#pragma unroll
    for (int i = 0; i < 4; ++i)
#pragma unroll
        for (int j = 0; j < 4; ++j) acc[i][j] = f32x4{0.f, 0.f, 0.f, 0.f};

#pragma unroll 1
    for (int k0 = 0; k0 < K; k0 += 32) {
        short8 a0 = ld8<AF32>(A, (size_t)(bm + r0), K, k0 + ko);
        short8 a1 = ld8<AF32>(A, (size_t)(bm + r1), K, k0 + ko);
        short8 b0 = ld8<BF32>(B, (size_t)(bn + r0), K, k0 + ko);
        short8 b1 = ld8<BF32>(B, (size_t)(bn + r1), K, k0 + ko);
        __syncthreads();
        *(short8*)&As[tid * 8]         = a0;
        *(short8*)&As[(tid + 256) * 8] = a1;
        *(short8*)&Bs[tid * 8]         = b0;
        *(short8*)&Bs[(tid + 256) * 8] = b1;
        __syncthreads();

        bf16x8 af[4], bfr[4];
#pragma unroll
        for (int i = 0; i < 4; ++i)
            af[i] = *(const bf16x8*)&As[(wm + i * 16 + col) * 32 + quad * 8];
#pragma unroll
        for (int j = 0; j < 4; ++j)
            bfr[j] = *(const bf16x8*)&Bs[(wn + j * 16 + col) * 32 + quad * 8];
#pragma unroll
        for (int i = 0; i < 4; ++i)
#pragma unroll
            for (int j = 0; j < 4; ++j)
                acc[i][j] = MFMA16(af[i], bfr[j], acc[i][j]);
    }
}

// ---------------------------------------------------------------------------
// GEMM core (bf16, global_load_lds staging — m97 structure).
// ---------------------------------------------------------------------------
__device__ __forceinline__ void gemm128_lds(
    const short* __restrict__ A, const short* __restrict__ B, int K,
    short* As, short* Bs, int bm, int bn, f32x4 acc[4][4]) {
    const int tid  = threadIdx.x;
    const int lane = tid & 63;
    const int wave = tid >> 6;
    const int quad = lane >> 4;
    const int col  = lane & 15;
    const int wm   = (wave & 1) * 64;
    const int wn   = (wave >> 1) * 64;

    const int r0 = tid >> 2;            // 0..63
    const int r1 = r0 + 64;             // 64..127
    const int ko = (tid & 3) * 8;

    const short* A0 = &A[(size_t)(bm + r0) * K + ko];
    const short* A1 = &A[(size_t)(bm + r1) * K + ko];
    const short* B0 = &B[(size_t)(bn + r0) * K + ko];
    const short* B1 = &B[(size_t)(bn + r1) * K + ko];

    short* As0 = &As[wave * 512];          // wave base, first half
    short* As1 = &As[2048 + wave * 512];   // second half (+4096 B)
    short* Bs0 = &Bs[wave * 512];
    short* Bs1 = &Bs[2048 + wave * 512];

#pragma unroll
    for (int i = 0; i < 4; ++i)
#pragma unroll
        for (int j = 0; j < 4; ++j) acc[i][j] = f32x4{0.f, 0.f, 0.f, 0.f};

#pragma unroll 1
    for (int k0 = 0; k0 < K; k0 += 32) {
        __syncthreads();                   // prev step's LDS reads done
        gload16(A0 + k0, As0);
        gload16(A1 + k0, As1);
        gload16(B0 + k0, Bs0);
        gload16(B1 + k0, Bs1);
        __syncthreads();                   // vmcnt drained -> tile staged

        bf16x8 af[4], bfr[4];
#pragma unroll
        for (int i = 0; i < 4; ++i)
            af[i] = *(const bf16x8*)&As[(wm + i * 16 + col) * 32 + quad * 8];
#pragma unroll
        for (int j = 0; j < 4; ++j)
            bfr[j] = *(const bf16x8*)&Bs[(wn + j * 16 + col) * 32 + quad * 8];
#pragma unroll
        for (int i = 0; i < 4; ++i)
#pragma unroll
            for (int j = 0; j < 4; ++j)
                acc[i][j] = MFMA16(af[i], bfr[j], acc[i][j]);
    }
}

// ---------------------------------------------------------------------------
// K1: QKV GEMM + RoPE. grid=(24, 64). Q,K row-major [B,H,S,D]; V transposed
// [B,H,D,S] (round-4 direct-store epilogue; LDS-staged variant was neutral).
// ---------------------------------------------------------------------------
template <bool PRE>
__global__ __launch_bounds__(256, 2) void qkv_rope_kernel(
    const void* __restrict__ X, const void* __restrict__ W,
    const float* __restrict__ cosT, const float* __restrict__ sinT,
    short* __restrict__ Qo, short* __restrict__ Ko, short* __restrict__ VT) {
    __shared__ __align__(16) short As[128 * 32];
    __shared__ __align__(16) short Bs[128 * 32];
    const int bm = blockIdx.y * 128, bn = blockIdx.x * 128;
    const int lane = threadIdx.x & 63, wave = threadIdx.x >> 6;
    const int quad = lane >> 4, col = lane & 15;
    const int wm = (wave & 1) * 64, wn = (wave >> 1) * 64;

    f32x4 acc[4][4];
    if constexpr (PRE)
        gemm128_lds((const short*)X, (const short*)W, 1024, As, Bs, bm, bn, acc);
    else
        gemm128_core<true, true>(X, W, 1024, As, Bs, bm, bn, acc);

    const int n0    = bn + wn;       // 64-aligned -> which/h wave-uniform
    const int which = n0 >> 10;      // 0=q 1=k 2=v
    const int h     = (n0 >> 6) & 15;

    if (which == 2) {
        // V^T: VT[((b*NH+h)*HD + d)*SEQ + s], 4 consecutive s per 8B store
#pragma unroll
        for (int i = 0; i < 4; ++i) {
            int    m = bm + wm + i * 16 + quad * 4;    // s of reg 0
            int    b = m >> 11, s = m & 2047;
            size_t rowb = (size_t)(b * NH + h) * HD;
#pragma unroll
            for (int j = 0; j < 4; ++j) {
                int   d = j * 16 + col;
                s16x4 pk;
                pk[0] = f2bf(acc[i][j][0]); pk[1] = f2bf(acc[i][j][1]);
                pk[2] = f2bf(acc[i][j][2]); pk[3] = f2bf(acc[i][j][3]);
                *(s16x4*)&VT[(rowb + d) * SEQ + s] = pk;
            }
        }
    } else {
        short* dst = which ? Ko : Qo;
#pragma unroll
        for (int i = 0; i < 4; ++i)
#pragma unroll
            for (int reg = 0; reg < 4; ++reg) {
                int    m = bm + wm + i * 16 + quad * 4 + reg;
                int    b = m >> 11, s = m & 2047;
                size_t base = ((size_t)(b * NH + h) * SEQ + s) * HD;
#pragma unroll
                for (int j = 0; j < 2; ++j) {
                    int   d1 = j * 16 + col;                        // 0..31
                    float sn, cs;
                    if constexpr (PRE) {
                        cs = cosT[(s << 5) + d1];
                        sn = sinT[(s << 5) + d1];
                    } else {
                        float inv = __expf(-0.28782313662425574f * (float)d1);
                        sincosf((float)s * inv, &sn, &cs);
                    }
                    float x1 = acc[i][j][reg];
                    float x2 = acc[i][j + 2][reg];
                    dst[base + d1]      = f2bf(x1 * cs - x2 * sn);
                    dst[base + d1 + 32] = f2bf(x1 * sn + x2 * cs);
                }
            }
    }
}

// ---------------------------------------------------------------------------
// K2: causal flash attention. grid=(16, 16, 4); block handles q-tiles
// {bx, 31-bx} -> exactly 33 t-iterations per block (balanced). Kt/Vt
// XOR-swizzled (conflicts 2.7e7 -> 1.1e6). Diag-only masking.
// Softmax: defer-max (T13, THR=8) + per-lane partial l_i (epilogue reduce).
// ---------------------------------------------------------------------------
__global__ __launch_bounds__(256, 2) void attn_kernel(
    const short* __restrict__ Q, const short* __restrict__ K,
    const short* __restrict__ VT, short* __restrict__ att) {
    const int b = blockIdx.z, h = blockIdx.y;
    const int tid = threadIdx.x, wave = tid >> 6, lane = tid & 63;
    const int quad = lane >> 4, col = lane & 15;
    const size_t hoff = (size_t)(b * NH + h) * SEQ * HD;
    const short* Qp  = Q + hoff;
    const short* Kp  = K + hoff;
    const short* VTp = VT + hoff;   // [HD][SEQ]

    __shared__ __align__(16) short Kt[64 * 64];        // [t][d], swizzled
    __shared__ __align__(16) short Vt[64 * 64];        // [d][t], swizzled
    __shared__ __align__(16) short Ps[4 * 16 * PS_LD]; // per-wave P [m][k], padded

    const int r0 = tid >> 3;            // 0..31
    const int r1 = r0 + 32;             // 32..63  (r1&7 == r0&7)
    const int c8 = (tid & 7) * 8;
    const int cs = c8 ^ ((r0 & 7) << 3);            // swizzled store column
    const int swc = (col & 7) << 3;
    const int cA  = (quad * 8) ^ swc;               // first half of row
    const int cB  = (32 + quad * 8) ^ swc;          // second half of row
    short* Pw = &Ps[wave * 16 * PS_LD];

#pragma unroll 1
    for (int pass = 0; pass < 2; ++pass) {
        const int qt = pass ? 31 - (int)blockIdx.x : (int)blockIdx.x;
        const int q0 = qt * 64 + wave * 16;

        bf16x8 aq0 = *(const bf16x8*)&Qp[(q0 + col) * HD + quad * 8];
        bf16x8 aq1 = *(const bf16x8*)&Qp[(q0 + col) * HD + 32 + quad * 8];

        float m_i[4], l_i[4];
        f32x4 o[4];
#pragma unroll
        for (int r = 0; r < 4; ++r) { m_i[r] = NEGINF; l_i[r] = 0.f; o[r] = f32x4{0.f, 0.f, 0.f, 0.f}; }

        // prefetch tile 0
        short8 ka = *(const short8*)&Kp[r0 * HD + c8];
        short8 kb = *(const short8*)&Kp[r1 * HD + c8];
        short8 va = *(const short8*)&VTp[(size_t)r0 * SEQ + c8];
        short8 vb = *(const short8*)&VTp[(size_t)r1 * SEQ + c8];

#pragma unroll 1
        for (int t = 0; t <= qt; ++t) {
            const int kt = t * 64;
            __syncthreads();                       // prev iter's LDS reads done
            *(short8*)&Kt[r0 * 64 + cs] = ka;
            *(short8*)&Kt[r1 * 64 + cs] = kb;
            *(short8*)&Vt[r0 * 64 + cs] = va;
            *(short8*)&Vt[r1 * 64 + cs] = vb;
            __syncthreads();                       // tile staged

            if (t < qt) {                          // prefetch next tile
                const int kn = kt + 64;
                ka = *(const short8*)&Kp[(kn + r0) * HD + c8];
                kb = *(const short8*)&Kp[(kn + r1) * HD + c8];
                va = *(const short8*)&VTp[(size_t)r0 * SEQ + kn + c8];
                vb = *(const short8*)&VTp[(size_t)r1 * SEQ + kn + c8];
            }

            // S = Q K^T / 8; mask only needed on the diagonal tile
            float p[4][4];  // [jn][reg]
#pragma unroll
            for (int jn = 0; jn < 4; ++jn) {
                f32x4  s  = f32x4{0.f, 0.f, 0.f, 0.f};
                bf16x8 b0 = *(const bf16x8*)&Kt[(jn * 16 + col) * 64 + cA];
                bf16x8 b1 = *(const bf16x8*)&Kt[(jn * 16 + col) * 64 + cB];
                s = MFMA16(aq0, b0, s);
                s = MFMA16(aq1, b1, s);
                if (t == qt) {                     // wave-uniform branch
#pragma unroll
                    for (int reg = 0; reg < 4; ++reg) {
                        int qr = wave * 16 + quad * 4 + reg;   // local row
                        int kc = jn * 16 + col;                // local col
                        p[jn][reg] = (kc <= qr) ? s[reg] * 0.125f : NEGINF;
                    }
                } else {
#pragma unroll
                    for (int reg = 0; reg < 4; ++reg) p[jn][reg] = s[reg] * 0.125f;
                }
            }

            // --- softmax: defer-max (THR=8) + per-lane partial l_i ---
            float lm[4];
#pragma unroll
            for (int reg = 0; reg < 4; ++reg)
                lm[reg] = fmaxf(fmaxf(p[0][reg], p[1][reg]), fmaxf(p[2][reg], p[3][reg]));
            int ok = (lm[0] <= m_i[0] + 8.f) & (lm[1] <= m_i[1] + 8.f) &
                     (lm[2] <= m_i[2] + 8.f) & (lm[3] <= m_i[3] + 8.f);
            if (__all(ok)) {
                // cheap path: no max-reduce, no alpha, no rescale
#pragma unroll
                for (int reg = 0; reg < 4; ++reg) {
                    float rs = 0.f;
#pragma unroll
                    for (int jn = 0; jn < 4; ++jn) {
                        p[jn][reg] = __expf(p[jn][reg] - m_i[reg]);
                        rs += p[jn][reg];
                    }
                    l_i[reg] += rs;                // per-lane partial
                }
            } else {
                float alpha[4];
#pragma unroll
                for (int reg = 0; reg < 4; ++reg) {
                    float mx = lm[reg];
#pragma unroll
                    for (int off = 8; off >= 1; off >>= 1) mx = fmaxf(mx, __shfl_xor(mx, off, 64));
                    float mn   = fmaxf(m_i[reg], mx);
                    alpha[reg] = __expf(m_i[reg] - mn);
                    float rs = 0.f;
#pragma unroll
                    for (int jn = 0; jn < 4; ++jn) {
                        p[jn][reg] = __expf(p[jn][reg] - mn);
                        rs += p[jn][reg];
                    }
                    l_i[reg] = l_i[reg] * alpha[reg] + rs;   // per-lane partial
                    m_i[reg] = mn;
                }
#pragma unroll
                for (int jd = 0; jd < 4; ++jd)
#pragma unroll
                    for (int reg = 0; reg < 4; ++reg) o[jd][reg] *= alpha[reg];
            }

            // P: C-layout -> wave-private LDS [m][k] (padded stride; no barrier)
#pragma unroll
            for (int jn = 0; jn < 4; ++jn)
#pragma unroll
                for (int reg = 0; reg < 4; ++reg)
                    Pw[(quad * 4 + reg) * PS_LD + jn * 16 + col] = f2bf(p[jn][reg]);

            // O += P V
            bf16x8 ap0 = *(const bf16x8*)&Pw[col * PS_LD + quad * 8];
            bf16x8 ap1 = *(const bf16x8*)&Pw[col * PS_LD + 32 + quad * 8];
#pragma unroll
            for (int jd = 0; jd < 4; ++jd) {
                bf16x8 bv0 = *(const bf16x8*)&Vt[(jd * 16 + col) * 64 + cA];
                bf16x8 bv1 = *(const bf16x8*)&Vt[(jd * 16 + col) * 64 + cB];
                o[jd] = MFMA16(ap0, bv0, o[jd]);
                o[jd] = MFMA16(ap1, bv1, o[jd]);
            }
        }

        // epilogue: reduce per-lane l partials across the 16 col-lanes, then
        // att[b, s, h*64 + d] bf16
#pragma unroll
        for (int off = 8; off >= 1; off >>= 1)
#pragma unroll
            for (int reg = 0; reg < 4; ++reg)
                l_i[reg] += __shfl_xor(l_i[reg], off, 64);
        float inv_l[4];
#pragma unroll
        for (int reg = 0; reg < 4; ++reg) inv_l[reg] = 1.f / l_i[reg];
#pragma unroll
        for (int jd = 0; jd < 4; ++jd)
#pragma unroll
            for (int reg = 0; reg < 4; ++reg) {
                int s = q0 + quad * 4 + reg;
                att[((size_t)(b * SEQ + s)) * DIM + h * HD + jd * 16 + col] =
                    f2bf(o[jd][reg] * inv_l[reg]);
            }
    }
}

// ---------------------------------------------------------------------------
// K3: out = att @ Wout^T, FP32 output. grid=(8, 64). PRE: bf16 Wout + gload.
// ---------------------------------------------------------------------------
template <bool PRE>
__global__ __launch_bounds__(256, 2) void out_gemm_kernel(
    const short* __restrict__ A, const void* __restrict__ W,
    float* __restrict__ out) {
    __shared__ __align__(16) short As[128 * 32];
    __shared__ __align__(16) short Bs[128 * 32];
    const int bm = blockIdx.y * 128, bn = blockIdx.x * 128;
    const int lane = threadIdx.x & 63, wave = threadIdx.x >> 6;
    const int quad = lane >> 4, col = lane & 15;
    const int wm = (wave & 1) * 64, wn = (wave >> 1) * 64;

    f32x4 acc[4][4];
    if constexpr (PRE)
        gemm128_lds(A, (const short*)W, 1024, As, Bs, bm, bn, acc);
    else
        gemm128_core<false, true>(A, W, 1024, As, Bs, bm, bn, acc);

#pragma unroll
    for (int i = 0; i < 4; ++i)
#pragma unroll
        for (int reg = 0; reg < 4; ++reg) {
            int    m    = bm + wm + i * 16 + quad * 4 + reg;
            size_t base = (size_t)m * DIM + bn + wn;
#pragma unroll
            for (int j = 0; j < 4; ++j)
                out[base + j * 16 + col] = acc[i][j][reg];   // FP32 store
        }
}

// ---------------------------------------------------------------------------
extern "C" void kernel_launch(void* const* d_in, const int* in_sizes, int n_in,
                              void* d_out, int out_size, void* d_ws, size_t ws_size,
                              hipStream_t stream) {
    // Pointer assignment by unique element counts:
    //   x=8388608, mask=4194304 (tril, unused), Wqkv=3145728, Wout=1048576
    const float* x    = nullptr;
    const float* Wqkv = nullptr;
    const float* Wout = nullptr;
    for (int i = 0; i < n_in; ++i) {
        switch (in_sizes[i]) {
            case 8388608: x    = (const float*)d_in[i]; break;
            case 3145728: Wqkv = (const float*)d_in[i]; break;
            case 1048576: Wout = (const float*)d_in[i]; break;
            default: break;
        }
    }
    if (!x || !Wqkv || !Wout) return;

    short* Q  = (short*)d_ws;           // 16 MiB
    short* K  = Q + BHSD;               // 16 MiB
    short* VT = K + BHSD;               // 16 MiB (V transposed [B,H,D,S])
    float* out = (float*)d_out;

    const size_t need_pre = (size_t)4 * BHSD * sizeof(short)   // Q,K,VT,att
                          + BHSD * sizeof(short)               // Xb
                          + (size_t)3145728 * sizeof(short)    // Wqkvb
                          + (size_t)1048576 * sizeof(short)    // Woutb
                          + (size_t)2 * 65536 * sizeof(float); // tables

    if (ws_size >= need_pre) {
        short* att  = VT + BHSD;
        short* Xb   = att + BHSD;
        short* Wqb  = Xb + BHSD;
        short* Wob  = Wqb + 3145728;
        float* cosT = (float*)(Wob + 1048576);
        float* sinT = cosT + 65536;

        prep_kernel<<<dim3(2048), 256, 0, stream>>>(x, Wqkv, Wout, Xb, Wqb, Wob, cosT, sinT);
        qkv_rope_kernel<true><<<dim3(24, 64), 256, 0, stream>>>(Xb, Wqb, cosT, sinT, Q, K, VT);
        attn_kernel<<<dim3(16, NH, BATCH), 256, 0, stream>>>(Q, K, VT, att);
        out_gemm_kernel<true><<<dim3(8, 64), 256, 0, stream>>>(att, Wob, out);
    } else {
        // Fallback: fp32 staging + inline RoPE.
        qkv_rope_kernel<false><<<dim3(24, 64), 256, 0, stream>>>(
            x, Wqkv, nullptr, nullptr, Q, K, VT);

        const bool direct = ws_size >= (size_t)4 * BHSD * sizeof(short);
        short* att_dst = direct ? (VT + BHSD) : (short*)d_out;
        attn_kernel<<<dim3(16, NH, BATCH), 256, 0, stream>>>(Q, K, VT, att_dst);

        short* att = att_dst;
        if (!direct) {
            att = (short*)d_ws;         // reuse Q region after K2
            hipMemcpyAsync(att, att_dst, BHSD * sizeof(short), hipMemcpyDeviceToDevice, stream);
        }
        out_gemm_kernel<false><<<dim3(8, 64), 256, 0, stream>>>(att, Wout, out);
    }
}